// Round 5
// baseline (853.462 us; speedup 1.0000x reference)
//
#include <hip/hip_runtime.h>

#define IN_F 1024
#define OUT_F 1024
#define NTOK 32768
#define BM 256
#define BN 256
#define BK 32
#define KT (IN_F / BK)  // 32 K-tiles

typedef __bf16 bf16;
typedef __bf16 bf16x4 __attribute__((ext_vector_type(4)));
typedef __bf16 bf16x8 __attribute__((ext_vector_type(8)));
typedef float f32x4 __attribute__((ext_vector_type(4)));

// ---------------------------------------------------------------------------
// Kernel 1: build patched bf16 weight W' (validated rounds 1-4).
// ---------------------------------------------------------------------------
__global__ void build_wp(const float* __restrict__ W,
                         const int* __restrict__ rows,
                         const int* __restrict__ srcs,
                         const int* __restrict__ clones,
                         bf16* __restrict__ Wp) {
  const int r = blockIdx.x;
  const int row = rows[r];
  const int s = srcs[r];
  const int c0 = clones[3 * r + 0];
  const int c1 = clones[3 * r + 1];
  const int c2 = clones[3 * r + 2];
  const float* wr = W + (size_t)row * IN_F;
  const float fixv = 0.25f * (wr[s] + wr[c0] + wr[c1] + wr[c2]);

  const int col = threadIdx.x * 4;
  f32x4 v = *reinterpret_cast<const f32x4*>(wr + col);
  bf16x4 o;
#pragma unroll
  for (int j = 0; j < 4; ++j) {
    const int c = col + j;
    float f = v[j];
    if (c == c0 || c == c1 || c == c2) f = 0.0f;
    if (c == s) f = fixv;
    o[j] = (bf16)f;
  }
  *reinterpret_cast<bf16x4*>(Wp + (size_t)row * IN_F + col) = o;
}

// ---------------------------------------------------------------------------
// Kernel 2: out = X @ W'^T + bias.
// 256x256 tile, 8 waves (2Mx4N, per-wave 128x64), BK=32, double-buffered
// 64KB STATIC LDS -> 2 blocks/CU (512 blocks all co-resident; barrier stalls,
// prologue and epilogue of one block hide under the other block's compute).
// LDS rows are 64B (4 x 16B slots); swizzle: phys slot
//   p = s ^ ((row>>1)&3) ^ (((row>>3)&1)<<1)
// -> exactly 2 lanes/bank-group on ds_read_b128 (free, m136), <=2-way writes.
// A (fp32): global->reg (issued at tile start) -> cvt -> swizzled ds_write.
// B (bf16): global_load_lds, linear dest + pre-swizzled global source.
// ---------------------------------------------------------------------------
__global__ __launch_bounds__(512, 4) void gemm_rewire(
    const float* __restrict__ X, const bf16* __restrict__ Wp,
    const float* __restrict__ bias, float* __restrict__ out) {
  __shared__ __align__(16) bf16 lA[2][BM * BK];  // 16KB each
  __shared__ __align__(16) bf16 lB[2][BN * BK];  // 16KB each

  const int tid = threadIdx.x;
  const int lane = tid & 63;
  const int w = tid >> 6;   // 0..7
  const int wrow = w >> 2;  // 0..1  (128-row half of A)
  const int wcol = w & 3;   // 0..3  (64-col quarter of B)

  // XCD-grouped decode: 4 bn-sharers of an X-panel consecutive on same XCD.
  const int bid = blockIdx.x;                // 0..511
  const int sq = bid >> 3;                   // 0..63
  const int bm = (bid & 7) + 8 * (sq >> 2);  // 0..127
  const int bn = sq & 3;                     // 0..3

  // --- A staging: thread owns row tid>>1, fp32 cols (tid&1)*16 .. +16
  const float* gA = X + ((size_t)bm * BM + (tid >> 1)) * IN_F + (tid & 1) * 16;
  // A ds_write: row = tid>>1; logical slots s0=(tid&1)*2, s0+1
  const int awrow = tid >> 1;
  const int axs = ((tid >> 2) & 3) ^ (((tid >> 4) & 1) << 1);  // XS(row)

  // --- B staging: linear gload_lds dest; pre-swizzled global source.
  // issue i: LDS row = i*128 + w*16 + (lane>>2), phys slot = lane&3
  // logical slot s = p ^ XS(row), XS(row) = ((lane>>3)&3) ^ (((lane>>5)&1)<<1)
  {
  }
  const int bxs = ((lane >> 3) & 3) ^ (((lane >> 5) & 1) << 1);
  const bf16* gB = Wp + ((size_t)bn * BN + w * 16 + (lane >> 2)) * IN_F +
                   (((lane & 3) ^ bxs) << 3);

  // --- accumulators preloaded with bias (C/D col = lane&15)
  f32x4 acc[8][4];
#pragma unroll
  for (int n = 0; n < 4; ++n) {
    const float bv = bias[bn * BN + wcol * 64 + n * 16 + (lane & 15)];
#pragma unroll
    for (int m = 0; m < 8; ++m) acc[m][n] = (f32x4){bv, bv, bv, bv};
  }

  // --- fragment read geometry: row = base + (lane&15) + {m,n}*16.
  // XS(row) depends only on (lane&15) here (higher terms are ≡0 mod its bits).
  const int rl = lane & 15;
  const int rxs = ((rl >> 1) & 3) ^ (((rl >> 3) & 1) << 1);
  const int so = (((lane >> 4) ^ rxs) << 4);  // swizzled 16B slot byte offset
  const int arow0 = wrow * 128 + rl;          // + m*16
  const int brow0 = wcol * 64 + rl;           // + n*16

  f32x4 av[4];

  auto issueA = [&](int t) {
    const float* p = gA + (size_t)t * BK;
#pragma unroll
    for (int j = 0; j < 4; ++j)
      av[j] = *reinterpret_cast<const f32x4*>(p + j * 4);
  };
  auto writeA = [&](int buf) {
    char* base = (char*)lA[buf] + awrow * 64;
#pragma unroll
    for (int j = 0; j < 2; ++j) {
      bf16x8 o;
#pragma unroll
      for (int q = 0; q < 4; ++q) {
        o[q] = (bf16)av[2 * j][q];
        o[4 + q] = (bf16)av[2 * j + 1][q];
      }
      const int s = (tid & 1) * 2 + j;
      *reinterpret_cast<bf16x8*>(base + ((s ^ axs) << 4)) = o;
    }
  };
  auto issueB = [&](int t, int buf) {
    const bf16* g = gB + (size_t)t * BK;
#pragma unroll
    for (int i = 0; i < 2; ++i) {
      char* dst = (char*)lB[buf] + i * 8192 + w * 1024;  // wave-uniform base
      __builtin_amdgcn_global_load_lds(
          (const __attribute__((address_space(1))) void*)(g +
                                                          (size_t)i * 128 * IN_F),
          (__attribute__((address_space(3))) void*)dst, 16, 0, 0);
    }
  };
  auto compute = [&](int buf) {
    const char* A = (const char*)lA[buf];
    const char* B = (const char*)lB[buf];
    bf16x8 af[8], bfr[4];
#pragma unroll
    for (int m = 0; m < 8; ++m)
      af[m] = *reinterpret_cast<const bf16x8*>(A + (arow0 + m * 16) * 64 + so);
#pragma unroll
    for (int n = 0; n < 4; ++n)
      bfr[n] = *reinterpret_cast<const bf16x8*>(B + (brow0 + n * 16) * 64 + so);
    __builtin_amdgcn_s_setprio(1);
#pragma unroll
    for (int m = 0; m < 8; ++m)
#pragma unroll
      for (int n = 0; n < 4; ++n)
        acc[m][n] = __builtin_amdgcn_mfma_f32_16x16x32_bf16(af[m], bfr[n],
                                                            acc[m][n], 0, 0, 0);
    __builtin_amdgcn_s_setprio(0);
  };

  // --- prologue: stage tile 0 into buffer 0
  issueA(0);
  issueB(0, 0);
  writeA(0);        // compiler inserts vmcnt wait for av
  __syncthreads();  // drains B(0) gloads + ds_writes

  // --- main loop: one barrier per K-tile
  for (int t = 0; t < KT; ++t) {
    const int db = t & 1;
    const bool more = (t + 1) < KT;
    if (more) {
      issueA(t + 1);          // 4 dwordx4 -> regs (in flight through compute)
      issueB(t + 1, db ^ 1);  // 2 gload_lds -> other buffer
      __builtin_amdgcn_sched_barrier(0);
    }
    compute(db);
    if (more) {
      __builtin_amdgcn_sched_barrier(0);  // keep MFMAs above the cvt/write
      writeA(db ^ 1);   // waits A-loads only, leaves B gloads in flight
      __syncthreads();  // tile boundary (loads landed under compute)
    }
  }

  // --- epilogue: C/D layout col = lane&15, row = (lane>>4)*4 + i
  const int orow0 = bm * BM + wrow * 128 + (lane >> 4) * 4;
  const int ocol = bn * BN + wcol * 64 + (lane & 15);
#pragma unroll
  for (int m = 0; m < 8; ++m) {
#pragma unroll
    for (int n = 0; n < 4; ++n) {
      const f32x4 v = acc[m][n];
      const size_t base = (size_t)(orow0 + m * 16) * OUT_F + (ocol + n * 16);
#pragma unroll
      for (int i = 0; i < 4; ++i) out[base + (size_t)i * OUT_F] = v[i];
    }
  }
}

// ---------------------------------------------------------------------------
extern "C" void kernel_launch(void* const* d_in, const int* in_sizes, int n_in,
                              void* d_out, int out_size, void* d_ws,
                              size_t ws_size, hipStream_t stream) {
  const float* x = (const float*)d_in[0];
  const float* weight = (const float*)d_in[1];
  const float* bias = (const float*)d_in[2];
  const int* rrows = (const int*)d_in[3];
  const int* rsrc = (const int*)d_in[4];
  const int* rclones = (const int*)d_in[5];
  float* out = (float*)d_out;
  bf16* Wp = (bf16*)d_ws;  // 2 MB scratch

  build_wp<<<dim3(OUT_F), dim3(256), 0, stream>>>(weight, rrows, rsrc, rclones,
                                                  Wp);
  gemm_rewire<<<dim3((NTOK / BM) * (OUT_F / BN)), dim3(512), 0, stream>>>(
      x, Wp, bias, out);
}

// Round 6
// 288.823 us; speedup vs baseline: 2.9550x; 2.9550x over previous
//
#include <hip/hip_runtime.h>

#define IN_F 1024
#define OUT_F 1024
#define NTOK 32768
#define BMT 64    // block tile M
#define BNT 256   // block tile N (4 waves x 64 cols)
#define BK 64
#define KT (IN_F / BK)  // 16 K-tiles

typedef __bf16 bf16;
typedef __bf16 bf16x4 __attribute__((ext_vector_type(4)));
typedef __bf16 bf16x8 __attribute__((ext_vector_type(8)));
typedef float f32x4 __attribute__((ext_vector_type(4)));

// ---------------------------------------------------------------------------
// Kernel 1: build patched bf16 weight W' (validated rounds 1-5).
// ---------------------------------------------------------------------------
__global__ void build_wp(const float* __restrict__ W,
                         const int* __restrict__ rows,
                         const int* __restrict__ srcs,
                         const int* __restrict__ clones,
                         bf16* __restrict__ Wp) {
  const int r = blockIdx.x;
  const int row = rows[r];
  const int s = srcs[r];
  const int c0 = clones[3 * r + 0];
  const int c1 = clones[3 * r + 1];
  const int c2 = clones[3 * r + 2];
  const float* wr = W + (size_t)row * IN_F;
  const float fixv = 0.25f * (wr[s] + wr[c0] + wr[c1] + wr[c2]);

  const int col = threadIdx.x * 4;
  f32x4 v = *reinterpret_cast<const f32x4*>(wr + col);
  bf16x4 o;
#pragma unroll
  for (int j = 0; j < 4; ++j) {
    const int c = col + j;
    float f = v[j];
    if (c == c0 || c == c1 || c == c2) f = 0.0f;
    if (c == s) f = fixv;
    o[j] = (bf16)f;
  }
  *reinterpret_cast<bf16x4*>(Wp + (size_t)row * IN_F + col) = o;
}

// ---------------------------------------------------------------------------
// Kernel 2: out = X @ W'^T + bias. HBM-roofline design (min traffic 259 MB).
//
// Block = 256 threads = 4 waves, tile 64(M) x 256(N); wave w owns 64x64.
// All 4 waves consume IDENTICAL A fragments -> A is loaded straight from
// global to registers (L1 dedups the 4x reuse); k-strides are compile-time
// immediates (t*256 + kk*128 bytes < 4096), so zero address math in the loop.
// A is fp32; convert to bf16 in-register after load (VALU pipe, hidden).
// B (bf16 Wp, 2 MB, L2-resident) double-buffered in LDS via global_load_lds
// (linear dest + pre-swizzled global source; slot_phys = s ^ (row&7) on
// 128B rows -> measured 0 bank conflicts in rounds 4/5).
// ONE __syncthreads per K-tile; no sched_barrier/vmcnt pins (m141), no
// setprio (symmetric waves). XCD-grouped decode: the 4 bn-sharers of each
// X-panel land on the same XCD -> X fetched from HBM exactly once.
// ---------------------------------------------------------------------------
__global__ __launch_bounds__(256, 2) void gemm_rewire(
    const float* __restrict__ X, const bf16* __restrict__ Wp,
    const float* __restrict__ bias, float* __restrict__ out) {
  __shared__ __align__(16) bf16 lB[2][BNT * BK];  // 32 KB each

  const int tid = threadIdx.x;
  const int lane = tid & 63;
  const int w = tid >> 6;  // 0..3 (N quarter)

  // XCD-grouped decode: 2048 blocks; xcd = bid&7 (HW round-robin);
  // per XCD: 64 bm-panels x 4 bn, bn fastest -> panel sharers adjacent.
  const int bid = blockIdx.x;                // 0..2047
  const int seq = bid >> 3;                  // 0..255
  const int bm = (bid & 7) + 8 * (seq >> 2); // 0..511
  const int bn = seq & 3;                    // 0..3

  // --- A per-lane base: row = bm*64 + (lane&15), k0 = (lane>>4)*8 floats.
  const float* gA =
      X + ((size_t)bm * BMT + (lane & 15)) * IN_F + (lane >> 4) * 8;

  // --- B staging source (pre-swizzled): issue i covers LDS rows
  // i*32 + w*8 + (lane>>3), phys 16B-slot lane&7; logical slot = phys ^ (row&7).
  const bf16* gB = Wp + ((size_t)bn * BNT + w * 8 + (lane >> 3)) * IN_F +
                   (((lane & 7) ^ ((lane >> 3) & 7)) * 8);

  // --- accumulators preloaded with bias (C/D col = lane&15)
  f32x4 acc[4][4];
#pragma unroll
  for (int n = 0; n < 4; ++n) {
    const float bv = bias[bn * BNT + w * 64 + n * 16 + (lane & 15)];
#pragma unroll
    for (int m = 0; m < 4; ++m) acc[m][n] = (f32x4){bv, bv, bv, bv};
  }

  // --- B fragment geometry: col = w*64 + n*16 + (lane&15) (col&7 == lane&7),
  // slot = kk*4 + (lane>>4), byte = col*128 + ((slot ^ (lane&7)) * 16).
  const int bcol0 = w * 64 + (lane & 15);
  const int lx7 = lane & 7;
  const int sl0 = lane >> 4;

  auto issueB = [&](int t, int buf) {
    const bf16* g = gB + t * BK;
#pragma unroll
    for (int i = 0; i < 8; ++i) {
      char* dst = (char*)lB[buf] + i * 4096 + w * 1024;  // wave-uniform base
      __builtin_amdgcn_global_load_lds(
          (const __attribute__((address_space(1))) void*)(g +
                                                          (size_t)i * 32 * IN_F),
          (__attribute__((address_space(3))) void*)dst, 16, 0, 0);
    }
  };

  // --- prologue: stage B(0)
  issueB(0, 0);
  __syncthreads();

#pragma unroll
  for (int t = 0; t < KT; ++t) {
    // A fragments for THIS tile: compile-time offsets, straight from global.
    f32x4 av[4][2][2];
#pragma unroll
    for (int m = 0; m < 4; ++m)
#pragma unroll
      for (int kk = 0; kk < 2; ++kk) {
        const float* p = gA + (size_t)m * 16 * IN_F + t * BK + kk * 32;
        av[m][kk][0] = *reinterpret_cast<const f32x4*>(p);
        av[m][kk][1] = *reinterpret_cast<const f32x4*>(p + 4);
      }
    // stage B for next tile into the other buffer (in flight through compute)
    if (t + 1 < KT) issueB(t + 1, (t + 1) & 1);

    const char* B = (const char*)lB[t & 1];
#pragma unroll
    for (int kk = 0; kk < 2; ++kk) {
      bf16x8 bfr[4];
#pragma unroll
      for (int n = 0; n < 4; ++n) {
        const int col = bcol0 + n * 16;
        bfr[n] = *reinterpret_cast<const bf16x8*>(
            B + col * 128 + (((kk * 4 + sl0) ^ lx7) * 16));
      }
#pragma unroll
      for (int m = 0; m < 4; ++m) {
        bf16x8 af;
#pragma unroll
        for (int q = 0; q < 4; ++q) {
          af[q] = (bf16)av[m][kk][0][q];
          af[4 + q] = (bf16)av[m][kk][1][q];
        }
#pragma unroll
        for (int n = 0; n < 4; ++n)
          acc[m][n] = __builtin_amdgcn_mfma_f32_16x16x32_bf16(af, bfr[n],
                                                              acc[m][n], 0, 0, 0);
      }
    }
    __syncthreads();  // B(t+1) landed (full compute of flight); buffers safe
  }

  // --- epilogue: C/D layout col = lane&15, row = (lane>>4)*4 + i
  const int orow0 = bm * BMT + (lane >> 4) * 4;
  const int ocol = bn * BNT + w * 64 + (lane & 15);
#pragma unroll
  for (int m = 0; m < 4; ++m) {
#pragma unroll
    for (int n = 0; n < 4; ++n) {
      const f32x4 v = acc[m][n];
      const size_t base = (size_t)(orow0 + m * 16) * OUT_F + (ocol + n * 16);
#pragma unroll
      for (int i = 0; i < 4; ++i) out[base + (size_t)i * OUT_F] = v[i];
    }
  }
}

// ---------------------------------------------------------------------------
extern "C" void kernel_launch(void* const* d_in, const int* in_sizes, int n_in,
                              void* d_out, int out_size, void* d_ws,
                              size_t ws_size, hipStream_t stream) {
  const float* x = (const float*)d_in[0];
  const float* weight = (const float*)d_in[1];
  const float* bias = (const float*)d_in[2];
  const int* rrows = (const int*)d_in[3];
  const int* rsrc = (const int*)d_in[4];
  const int* rclones = (const int*)d_in[5];
  float* out = (float*)d_out;
  bf16* Wp = (bf16*)d_ws;  // 2 MB scratch

  build_wp<<<dim3(OUT_F), dim3(256), 0, stream>>>(weight, rrows, rsrc, rclones,
                                                  Wp);
  gemm_rewire<<<dim3((NTOK / BMT) * (OUT_F / BNT)), dim3(256), 0, stream>>>(
      x, Wp, bias, out);
}

// Round 7
// 105.633 us; speedup vs baseline: 8.0795x; 2.7342x over previous
//
#include <hip/hip_runtime.h>

#define IN_F 1024
#define OUT_F 1024
#define NTOK 32768
#define BM 256
#define BN 256
#define BK 64
#define KT (IN_F / BK)  // 16 K-tiles
#define NITER (KT / 2)  // 8 iterations, 2 K-tiles each

typedef __bf16 bf16;
typedef __bf16 bf16x4 __attribute__((ext_vector_type(4)));
typedef __bf16 bf16x8 __attribute__((ext_vector_type(8)));
typedef float f32x4 __attribute__((ext_vector_type(4)));

// LDS byte offsets: A-parity buffers then B-parity buffers (32 KB each).
#define LDS_A0 0
#define LDS_A1 32768
#define LDS_B0 65536
#define LDS_B1 98304

// ---------------------------------------------------------------------------
// Kernel 1: build patched bf16 weight W' (validated rounds 1-6).
// ---------------------------------------------------------------------------
__global__ void build_wp(const float* __restrict__ W,
                         const int* __restrict__ rows,
                         const int* __restrict__ srcs,
                         const int* __restrict__ clones,
                         bf16* __restrict__ Wp) {
  const int r = blockIdx.x;
  const int row = rows[r];
  const int s = srcs[r];
  const int c0 = clones[3 * r + 0];
  const int c1 = clones[3 * r + 1];
  const int c2 = clones[3 * r + 2];
  const float* wr = W + (size_t)row * IN_F;
  const float fixv = 0.25f * (wr[s] + wr[c0] + wr[c1] + wr[c2]);

  const int col = threadIdx.x * 4;
  f32x4 v = *reinterpret_cast<const f32x4*>(wr + col);
  bf16x4 o;
#pragma unroll
  for (int j = 0; j < 4; ++j) {
    const int c = col + j;
    float f = v[j];
    if (c == c0 || c == c1 || c == c2) f = 0.0f;
    if (c == s) f = fixv;
    o[j] = (bf16)f;
  }
  *reinterpret_cast<bf16x4*>(Wp + (size_t)row * IN_F + col) = o;
}

// ---------------------------------------------------------------------------
// Kernel 2: out = X @ W'^T + bias — m201-style 8-phase schedule.
// 256x256 tile, 8 waves (2Mx4N, per-wave 128x64), BK=64, 128KB dynamic LDS.
// Iteration computes tiles ta=2i (bufs A0/B0, phases 0-3) and tb=2i+1
// (A1/B1, phases 4-7); each phase: {stage-chunk || ds_read subtile; barrier;
// lgkmcnt(0); setprio(1); 16 MFMA; setprio(0); [vmcnt(8) at ph3/ph7]; barrier}.
// A (fp32): loads issued 3-4 phases early -> cvt -> swizzled ds_write into the
// buffer freed by the preceding half-iteration. B (bf16 Wp): global_load_lds,
// linear dest + pre-swizzled source (round-4-validated, 0 bank conflicts).
// vmcnt(8) drains only the 4 B gload_lds; the 8 A-loads stay in flight.
// ---------------------------------------------------------------------------
__global__ __launch_bounds__(512, 2) void gemm_rewire(
    const float* __restrict__ X, const bf16* __restrict__ Wp,
    const float* __restrict__ bias, float* __restrict__ out) {
  extern __shared__ __align__(16) char smem[];

  const int tid = threadIdx.x;
  const int lane = tid & 63;
  const int w = tid >> 6;   // 0..7
  const int wrow = w >> 2;  // 0..1
  const int wcol = w & 3;   // 0..3

  // XCD-grouped decode (validated round 4: X panel fetched once per XCD).
  const int bid = blockIdx.x;                // 0..511
  const int sq = bid >> 3;                   // 0..63
  const int bm = (bid & 7) + 8 * (sq >> 2);  // 0..127
  const int bn = sq & 3;                     // 0..3

  // A staging: thread covers LDS rows (tid>>3)+j*64 (j=0..3), 16B at
  // fp32-col (tid&7)*8; swizzled write slot = (tid&7) ^ (row&7).
  const float* gA = X + ((size_t)bm * BM + (tid >> 3)) * IN_F + (tid & 7) * 8;
  const int awbyte =
      ((tid >> 3) << 7) + ((((tid & 7) ^ ((tid >> 3) & 7))) << 4);

  // B staging: linear gload_lds dest; pre-swizzled global source.
  const bf16* gB = Wp + ((size_t)bn * BN + w * 8 + (lane >> 3)) * IN_F +
                   (((lane & 7) ^ ((lane >> 3) & 7)) * 8);

  // Accumulators preloaded with bias (C/D col = lane&15).
  f32x4 acc[8][4];
#pragma unroll
  for (int n = 0; n < 4; ++n) {
    const float bv = bias[bn * BN + wcol * 64 + n * 16 + (lane & 15)];
#pragma unroll
    for (int m = 0; m < 8; ++m) acc[m][n] = (f32x4){bv, bv, bv, bv};
  }

  // Fragment read geometry (round-4-validated swizzle).
  const int rl = lane & 15;
  const int rx = rl & 7;
  const int arow0 = wrow * 128 + rl;  // + m*16
  const int brow0 = wcol * 64 + rl;   // + n*16
  const int sl0 = lane >> 4;          // + kk*4

  bf16x8 bfr[4][2];
  f32x4 aH0[4], aH1[4], aP0[4], aP1[4];

  auto loadAhalf = [&](int t, int h, f32x4 (&v)[4]) {
#pragma unroll
    for (int jj = 0; jj < 2; ++jj) {
      const float* p = gA + (size_t)(2 * h + jj) * 64 * IN_F + (size_t)t * BK;
      v[2 * jj] = *reinterpret_cast<const f32x4*>(p);
      v[2 * jj + 1] = *reinterpret_cast<const f32x4*>(p + 4);
    }
  };
  auto writeAhalf = [&](int bufOff, int h, const f32x4 (&v)[4]) {
#pragma unroll
    for (int jj = 0; jj < 2; ++jj) {
      bf16x8 o;
#pragma unroll
      for (int q = 0; q < 4; ++q) {
        o[q] = (bf16)v[2 * jj][q];
        o[4 + q] = (bf16)v[2 * jj + 1][q];
      }
      *reinterpret_cast<bf16x8*>(smem + bufOff + (2 * h + jj) * 8192 + awbyte) =
          o;
    }
  };
  auto issueBhalf = [&](int t, int bufOff, int h) {
#pragma unroll
    for (int ii = 0; ii < 2; ++ii) {
      const int i = 2 * h + ii;
      __builtin_amdgcn_global_load_lds(
          (const __attribute__((address_space(1))) void*)(gB + (size_t)t * BK +
                                                          (size_t)i * 64 * IN_F),
          (__attribute__((address_space(3))) void*)(smem + bufOff + i * 8192 +
                                                    w * 1024),
          16, 0, 0);
    }
  };
  auto readB = [&](int bufOff) {
#pragma unroll
    for (int n = 0; n < 4; ++n)
#pragma unroll
      for (int kk = 0; kk < 2; ++kk)
        bfr[n][kk] = *reinterpret_cast<const bf16x8*>(
            smem + bufOff + (brow0 + n * 16) * 128 +
            (((kk * 4 + sl0) ^ rx) << 4));
  };
  // One phase: af-subtile ds_read; barrier; lgkm(0); 16 MFMA; [endwait]; barrier
  // ew: 0 = none, 8 = vmcnt(8), 1 = vmcnt(0)  (placed BEFORE the closing
  // barrier so gload_lds-landed is published to all waves — race rule).
  auto phase = [&](int bufAOff, int m2, int ew) {
    bf16x8 af[2][2];
#pragma unroll
    for (int dm = 0; dm < 2; ++dm)
#pragma unroll
      for (int kk = 0; kk < 2; ++kk)
        af[dm][kk] = *reinterpret_cast<const bf16x8*>(
            smem + bufAOff + (arow0 + (m2 + dm) * 16) * 128 +
            (((kk * 4 + sl0) ^ rx) << 4));
    __builtin_amdgcn_s_barrier();
    asm volatile("s_waitcnt lgkmcnt(0)" ::: "memory");
    __builtin_amdgcn_sched_barrier(0);  // rule 18: keep MFMA below the wait
    __builtin_amdgcn_s_setprio(1);
#pragma unroll
    for (int dm = 0; dm < 2; ++dm)
#pragma unroll
      for (int n = 0; n < 4; ++n)
#pragma unroll
        for (int kk = 0; kk < 2; ++kk)
          acc[m2 + dm][n] = __builtin_amdgcn_mfma_f32_16x16x32_bf16(
              af[dm][kk], bfr[n][kk], acc[m2 + dm][n], 0, 0, 0);
    __builtin_amdgcn_s_setprio(0);
    if (ew == 8)
      asm volatile("s_waitcnt vmcnt(8)" ::: "memory");
    else if (ew == 1)
      asm volatile("s_waitcnt vmcnt(0)" ::: "memory");
    __builtin_amdgcn_s_barrier();
  };

  // --- prologue: tile0 -> A0/B0; A(1) -> aP regs.
  issueBhalf(0, LDS_B0, 0);
  issueBhalf(0, LDS_B0, 1);
  {
    f32x4 aZ0[4], aZ1[4];
    loadAhalf(0, 0, aZ0);
    loadAhalf(0, 1, aZ1);
    loadAhalf(1, 0, aP0);
    loadAhalf(1, 1, aP1);
    writeAhalf(LDS_A0, 0, aZ0);  // compiler inserts exact vmcnt for aZ
    writeAhalf(LDS_A0, 1, aZ1);
  }
  asm volatile("s_waitcnt vmcnt(8) lgkmcnt(0)" ::: "memory");  // B0 landed,
  __builtin_amdgcn_s_barrier();                                // aP in flight

  // --- main loop: 7 steady iterations + tail.
#pragma unroll 1
  for (int i = 0; i < NITER - 1; ++i) {
    const int tb = 2 * i + 1, ta2 = 2 * i + 2, tb2 = 2 * i + 3;
    // ph0: write A(tb) h0; stage B(tb) h0; read B-frags(tile ta)
    writeAhalf(LDS_A1, 0, aP0);
    issueBhalf(tb, LDS_B1, 0);
    readB(LDS_B0);
    phase(LDS_A0, 0, 0);
    // ph1
    writeAhalf(LDS_A1, 1, aP1);
    issueBhalf(tb, LDS_B1, 1);
    loadAhalf(ta2, 0, aH0);
    phase(LDS_A0, 2, 0);
    // ph2
    loadAhalf(ta2, 1, aH1);
    phase(LDS_A0, 4, 0);
    // ph3: vmcnt(8) drains B(tb) gload_lds, keeps 8 A-loads in flight
    phase(LDS_A0, 6, 8);
    // ph4: buf0 now free; write A(ta2) h0; stage B(ta2) h0
    writeAhalf(LDS_A0, 0, aH0);
    issueBhalf(ta2, LDS_B0, 0);
    readB(LDS_B1);
    phase(LDS_A1, 0, 0);
    // ph5
    writeAhalf(LDS_A0, 1, aH1);
    issueBhalf(ta2, LDS_B0, 1);
    loadAhalf(tb2, 0, aP0);
    phase(LDS_A1, 2, 0);
    // ph6
    loadAhalf(tb2, 1, aP1);
    phase(LDS_A1, 4, 0);
    // ph7: vmcnt(8) drains B(ta2), keeps A(tb2) loads in flight
    phase(LDS_A1, 6, 8);
  }
  // --- tail iteration (tiles 14,15): no staging beyond tile 15.
  writeAhalf(LDS_A1, 0, aP0);
  issueBhalf(KT - 1, LDS_B1, 0);
  readB(LDS_B0);
  phase(LDS_A0, 0, 0);
  writeAhalf(LDS_A1, 1, aP1);
  issueBhalf(KT - 1, LDS_B1, 1);
  phase(LDS_A0, 2, 0);
  phase(LDS_A0, 4, 0);
  phase(LDS_A0, 6, 1);  // vmcnt(0): B(15) landed
  readB(LDS_B1);
  phase(LDS_A1, 0, 0);
  phase(LDS_A1, 2, 0);
  phase(LDS_A1, 4, 0);
  phase(LDS_A1, 6, 0);

  // --- epilogue (round-4-validated): C/D col = lane&15, row = (lane>>4)*4+i
  const int orow0 = bm * BM + wrow * 128 + (lane >> 4) * 4;
  const int ocol = bn * BN + wcol * 64 + (lane & 15);
#pragma unroll
  for (int m = 0; m < 8; ++m) {
#pragma unroll
    for (int n = 0; n < 4; ++n) {
      const f32x4 v = acc[m][n];
      const size_t base = (size_t)(orow0 + m * 16) * OUT_F + (ocol + n * 16);
#pragma unroll
      for (int i = 0; i < 4; ++i) out[base + (size_t)i * OUT_F] = v[i];
    }
  }
}

// ---------------------------------------------------------------------------
extern "C" void kernel_launch(void* const* d_in, const int* in_sizes, int n_in,
                              void* d_out, int out_size, void* d_ws,
                              size_t ws_size, hipStream_t stream) {
  const float* x = (const float*)d_in[0];
  const float* weight = (const float*)d_in[1];
  const float* bias = (const float*)d_in[2];
  const int* rrows = (const int*)d_in[3];
  const int* rsrc = (const int*)d_in[4];
  const int* rclones = (const int*)d_in[5];
  float* out = (float*)d_out;
  bf16* Wp = (bf16*)d_ws;  // 2 MB scratch

  (void)hipFuncSetAttribute((const void*)gemm_rewire,
                            hipFuncAttributeMaxDynamicSharedMemorySize, 131072);

  build_wp<<<dim3(OUT_F), dim3(256), 0, stream>>>(weight, rrows, rsrc, rclones,
                                                  Wp);
  gemm_rewire<<<dim3((NTOK / BM) * (OUT_F / BN)), dim3(512), 131072, stream>>>(
      x, Wp, bias, out);
}